// Round 2
// baseline (17.209 us; speedup 1.0000x reference)
//
#include <hip/hip_runtime.h>
#include <hip/hip_bf16.h>

#define SUB 4  // threads cooperating per probe (each handles NATOM/SUB atoms)

__global__ __launch_bounds__(256) void gto_kernel(
    const float* __restrict__ probe,   // [Ptot,3] (Angstrom)
    const float* __restrict__ atom,    // [Atot,3]
    const int* __restrict__ n_probes,  // [B]
    const int* __restrict__ n_atoms,   // [B]
    const float* __restrict__ coeffs,  // [Atot,23]
    const float* __restrict__ expos,   // [9]
    float* __restrict__ out,           // [Ptot]
    int bsz, int ptot)
{
    const int t = blockIdx.x * blockDim.x + threadIdx.x;
    const int p = t / SUB;
    const int sub = t % SUB;
    if (p >= ptot) return;

    // ---- find batch of this probe (ragged-general; bsz=8 here) ----
    int poff = 0, aoff = 0, na = 0;
    for (int b = 0; b < bsz; ++b) {
        int np = n_probes[b];
        int nb = n_atoms[b];
        if (p < poff + np) { na = nb; break; }
        poff += np; aoff += nb;
    }

    // ---- per-orbital constants (uniform; recomputed per thread, once) ----
    // gammaln(l+1.5) for l=0,1,2
    const float gl[3] = {-0.12078223763524522f, 0.28468287047291918f, 1.2009736023470742f};
    const int   lsq[9] = {0,0,0,0,1,1,1,2,2};
    float e[9], ln[9];
#pragma unroll
    for (int k = 0; k < 9; ++k) {
        e[k] = expos[k];
        float pw = (float)lsq[k] + 1.5f;
        ln[k] = 0.5f * (pw * __logf(2.0f * e[k]) + 0.69314718055994531f - gl[lsq[k]]);
    }

    const float INV_BOHR = 1.8897259885789233f;  // 1/0.529177249
    const float S3 = 1.7320508075688772f;

    const float px = probe[p * 3 + 0];
    const float py = probe[p * 3 + 1];
    const float pz = probe[p * 3 + 2];

    float acc = 0.0f;
    for (int a = sub; a < na; a += SUB) {
        const int ai = aoff + a;
        const float ax = atom[ai * 3 + 0];
        const float ay = atom[ai * 3 + 1];
        const float az = atom[ai * 3 + 2];

        // vec = (probe - atom)[1,2,0] / BOHR2ANG
        const float x = (py - ay) * INV_BOHR;
        const float y = (pz - az) * INV_BOHR;
        const float z = (px - ax) * INV_BOHR;

        const float r2n = x * x + y * y + z * z;
        const float r   = sqrtf(r2n) + 1e-8f;   // reference EPSILON
        const float inv = 1.0f / r;
        const float ux = x * inv, uy = y * inv, uz = z * inv;
        const float rr = r * r;                  // reference uses (norm+eps)^2

        float rad[9];
#pragma unroll
        for (int k = 0; k < 9; ++k) rad[k] = __expf(ln[k] - e[k] * rr);
        rad[4] *= r;  rad[5] *= r;  rad[6] *= r;   // r^1 for l=1
        rad[7] *= rr; rad[8] *= rr;                // r^2 for l=2

        // spherical harmonics l=2 (e3nn 'norm' normalization)
        const float sh4 = S3 * ux * uz;
        const float sh5 = S3 * ux * uy;
        const float sh6 = uy * uy - 0.5f * (ux * ux + uz * uz);
        const float sh7 = S3 * uy * uz;
        const float sh8 = 0.5f * S3 * (uz * uz - ux * ux);

        const float* c = coeffs + ai * 23;
        float pp;
        pp  = rad[0] * c[0] + rad[1] * c[1] + rad[2] * c[2] + rad[3] * c[3];
        pp += rad[4] * (ux * c[4]  + uy * c[5]  + uz * c[6]);
        pp += rad[5] * (ux * c[7]  + uy * c[8]  + uz * c[9]);
        pp += rad[6] * (ux * c[10] + uy * c[11] + uz * c[12]);
        pp += rad[7] * (sh4 * c[13] + sh5 * c[14] + sh6 * c[15] + sh7 * c[16] + sh8 * c[17]);
        pp += rad[8] * (sh4 * c[18] + sh5 * c[19] + sh6 * c[20] + sh7 * c[21] + sh8 * c[22]);
        acc += pp;
    }

    // ---- reduce across the SUB lanes sharing this probe (consecutive lanes) ----
#pragma unroll
    for (int ofs = SUB / 2; ofs > 0; ofs >>= 1)
        acc += __shfl_xor(acc, ofs, 64);

    if (sub == 0) out[p] = acc;
}

extern "C" void kernel_launch(void* const* d_in, const int* in_sizes, int n_in,
                              void* d_out, int out_size, void* d_ws, size_t ws_size,
                              hipStream_t stream) {
    const float* probe  = (const float*)d_in[0];
    const float* atom   = (const float*)d_in[1];
    const int*   n_prb  = (const int*)d_in[2];
    const int*   n_atm  = (const int*)d_in[3];
    const float* coeffs = (const float*)d_in[4];
    const float* expos  = (const float*)d_in[5];
    float*       out    = (float*)d_out;

    const int bsz  = in_sizes[2];
    const int ptot = out_size;

    const int threads = ptot * SUB;
    const int block = 256;
    const int grid = (threads + block - 1) / block;
    gto_kernel<<<grid, block, 0, stream>>>(probe, atom, n_prb, n_atm, coeffs, expos, out, bsz, ptot);
}